// Round 2
// baseline (207.753 us; speedup 1.0000x reference)
//
#include <hip/hip_runtime.h>
#include <stdint.h>

namespace {

constexpr int kB = 256;
constexpr int kV = 128000;
constexpr int kSplit = 8;                       // V-chunks per row
constexpr int kBlk = 256;
constexpr int kChunk = kV / kSplit;             // 16000, divisible by 8
constexpr int kElem = 8;                        // elements per lane per iter

struct Part { float val; int idx; };

__device__ __forceinline__ uint32_t rotl32(uint32_t x, int r) {
  return (x << r) | (x >> (32 - r));
}

// JAX threefry2x32, key = (0, 42); partitionable mode: bits[i] = o0 ^ o1 of
// threefry(x0 = hi32(i) = 0, x1 = i). Verified bit-exact (absmax = 0).
// N-wide version: N independent counters interleaved ROUND-MAJOR so the
// instruction stream carries N parallel dependency chains (the scalar version
// compiled to VGPR_Count=16 -> chains were serialized -> latency-bound).
template <int N>
__device__ __forceinline__ void threefry_bits_n(uint32_t base, uint32_t* out) {
  constexpr uint32_t ks0 = 0u;
  constexpr uint32_t ks1 = 42u;
  constexpr uint32_t ks2 = 0x1BD11BDAu ^ ks0 ^ ks1;
  uint32_t x0[N], x1[N];
#pragma unroll
  for (int j = 0; j < N; ++j) { x0[j] = ks0; x1[j] = base + (uint32_t)j + ks1; }

#define TF_R(rr)                                                      \
  _Pragma("unroll")                                                   \
  for (int j = 0; j < N; ++j) {                                       \
    x0[j] += x1[j];                                                   \
    x1[j] = rotl32(x1[j], rr);                                        \
    x1[j] ^= x0[j];                                                   \
  }
#define TF_INJ(a, b)                                                  \
  _Pragma("unroll")                                                   \
  for (int j = 0; j < N; ++j) { x0[j] += (a); x1[j] += (b); }

  TF_R(13) TF_R(15) TF_R(26) TF_R(6)
  TF_INJ(ks1, ks2 + 1u)
  TF_R(17) TF_R(29) TF_R(16) TF_R(24)
  TF_INJ(ks2, ks0 + 2u)
  TF_R(13) TF_R(15) TF_R(26) TF_R(6)
  TF_INJ(ks0, ks1 + 3u)
  TF_R(17) TF_R(29) TF_R(16) TF_R(24)
  TF_INJ(ks1, ks2 + 4u)
  TF_R(13) TF_R(15) TF_R(26) TF_R(6)
  TF_INJ(ks2, ks0 + 5u)
#undef TF_R
#undef TF_INJ

#pragma unroll
  for (int j = 0; j < N; ++j) out[j] = x0[j] ^ x1[j];
}

// gumbel = -ln(-ln(u)).
// u: f = bitcast(bits>>9 | 0x3f800000) - 1 is exact (Sterbenz); ref's
// max(tiny, f + tiny) == fmaxf(f, tiny) bit-exactly (tiny << ulp(2^-23)).
// logs: -ln(-ln u) = -ln2*log2(-log2 u) - ln(ln2); the negate on the inner
// log2 result folds into v_log_f32's input modifier, the scale+offset is one
// fma. Native v_log_f32 (~1 ulp) error class identical to previous passing
// version (abs err in g ~5e-7 vs top-2 gumbel gaps O(1)).
__device__ __forceinline__ float gumbel_from_bits(uint32_t bits) {
  constexpr float kTiny = 1.17549435e-38f;   // FLT_MIN
  constexpr float kNegLn2 = -0.69314718055994530942f;
  constexpr float kNegLnLn2 = 0.36651292058166432701f;  // -ln(ln 2)
  float f = __uint_as_float((bits >> 9) | 0x3F800000u) - 1.0f;
  float u = fmaxf(f, kTiny);                  // == ref's max(tiny, f+tiny)
  float z = __builtin_amdgcn_logf(u);         // log2(u), <= ~-1.7e-7 < 0
  float w = __builtin_amdgcn_logf(-z);        // log2(-log2(u))
  return fmaf(kNegLn2, w, kNegLnLn2);         // -ln(-ln(u))
}

__global__ __launch_bounds__(kBlk, 8) void sampler_partial(
    const float* __restrict__ logits, const float* __restrict__ temps,
    Part* __restrict__ parts) {
  const int r = blockIdx.x / kSplit;
  const int g = blockIdx.x % kSplit;
  const float t = temps[r];
  const bool greedy = (t == 0.0f);
  const int start = g * kChunk;
  const int end = start + kChunk;
  const float* __restrict__ row = logits + (size_t)r * kV;

  float best = -__builtin_inff();
  int bi = 0;

  if (greedy) {
    // pure argmax of raw logits, first-occurrence tie-break (strict >)
    for (int v = start + (int)threadIdx.x * kElem; v + (kElem - 1) < end;
         v += kBlk * kElem) {
      float4 a = *reinterpret_cast<const float4*>(row + v);
      float4 b = *reinterpret_cast<const float4*>(row + v + 4);
      float la[8] = {a.x, a.y, a.z, a.w, b.x, b.y, b.z, b.w};
#pragma unroll
      for (int j = 0; j < 8; ++j) {
        if (la[j] > best) { best = la[j]; bi = v + j; }
      }
    }
  } else {
    // argmax(la/t + g) == argmax(la + t*g) for t > 0 (monotonic, real arith).
    for (int v = start + (int)threadIdx.x * kElem; v + (kElem - 1) < end;
         v += kBlk * kElem) {
      float4 a = *reinterpret_cast<const float4*>(row + v);
      float4 b = *reinterpret_cast<const float4*>(row + v + 4);
      float la[8] = {a.x, a.y, a.z, a.w, b.x, b.y, b.z, b.w};
      uint32_t bits[8];
      threefry_bits_n<8>((uint32_t)(r * kV + v), bits);  // flat idx < 2^25
#pragma unroll
      for (int j = 0; j < 8; ++j) {
        float key = fmaf(t, gumbel_from_bits(bits[j]), la[j]);
        if (key > best) { best = key; bi = v + j; }
      }
    }
  }

  __shared__ float sv[kBlk];
  __shared__ int si[kBlk];
  sv[threadIdx.x] = best;
  si[threadIdx.x] = bi;
  __syncthreads();
  for (int s = kBlk / 2; s > 0; s >>= 1) {
    if ((int)threadIdx.x < s) {
      float ov = sv[threadIdx.x + s]; int oi = si[threadIdx.x + s];
      float mv = sv[threadIdx.x];     int mi = si[threadIdx.x];
      if (ov > mv || (ov == mv && oi < mi)) {
        sv[threadIdx.x] = ov; si[threadIdx.x] = oi;
      }
    }
    __syncthreads();
  }
  if (threadIdx.x == 0) {
    parts[r * kSplit + g].val = sv[0];
    parts[r * kSplit + g].idx = si[0];
  }
}

__global__ __launch_bounds__(kB) void sampler_final(
    const Part* __restrict__ parts, int* __restrict__ out) {
  const int r = threadIdx.x;
  if (r < kB) {
    float bv = -__builtin_inff();
    int bi = 0;
    for (int g = 0; g < kSplit; ++g) {
      Part p = parts[r * kSplit + g];
      if (p.val > bv || (p.val == bv && p.idx < bi)) { bv = p.val; bi = p.idx; }
    }
    out[r] = bi;
  }
}

}  // namespace

extern "C" void kernel_launch(void* const* d_in, const int* in_sizes, int n_in,
                              void* d_out, int out_size, void* d_ws, size_t ws_size,
                              hipStream_t stream) {
  const float* logits = (const float*)d_in[0];
  const float* temps = (const float*)d_in[1];
  int* out = (int*)d_out;
  Part* parts = (Part*)d_ws;  // kB * kSplit * 8 B = 16 KiB

  sampler_partial<<<dim3(kB * kSplit), dim3(kBlk), 0, stream>>>(logits, temps, parts);
  sampler_final<<<dim3(1), dim3(kB), 0, stream>>>(parts, out);
}

// Round 3
// 206.722 us; speedup vs baseline: 1.0050x; 1.0050x over previous
//
#include <hip/hip_runtime.h>
#include <stdint.h>

namespace {

constexpr int kB = 256;
constexpr int kV = 128000;
constexpr int kSplit = 8;                       // V-chunks per row
constexpr int kBlk = 256;
constexpr int kChunk = kV / kSplit;             // 16000, divisible by 8
constexpr int kElem = 8;                        // elements per lane per iter

struct Part { float val; int idx; };

__device__ __forceinline__ uint32_t rotl32(uint32_t x, int r) {
  return (x << r) | (x >> (32 - r));
}

// JAX threefry2x32, key = (0, 42); partitionable mode: bits[i] = o0 ^ o1 of
// threefry(x0 = hi32(i) = 0, x1 = i). Verified bit-exact (absmax = 0, R0/R2).
// 8-wide round-major interleave: 8 independent dependency chains in the
// instruction stream. R2 lesson: __launch_bounds__(256,8) capped VGPRs at 32
// -> compiler re-serialized the chains; this build uncaps (min-waves 2).
template <int N>
__device__ __forceinline__ void threefry_bits_n(uint32_t base, uint32_t* out) {
  constexpr uint32_t ks0 = 0u;
  constexpr uint32_t ks1 = 42u;
  constexpr uint32_t ks2 = 0x1BD11BDAu ^ ks0 ^ ks1;
  uint32_t x0[N], x1[N];
#pragma unroll
  for (int j = 0; j < N; ++j) { x0[j] = ks0; x1[j] = base + (uint32_t)j + ks1; }

#define TF_R(rr)                                                      \
  _Pragma("unroll")                                                   \
  for (int j = 0; j < N; ++j) {                                       \
    x0[j] += x1[j];                                                   \
    x1[j] = rotl32(x1[j], rr);                                        \
    x1[j] ^= x0[j];                                                   \
  }
#define TF_INJ(a, b)                                                  \
  _Pragma("unroll")                                                   \
  for (int j = 0; j < N; ++j) { x0[j] += (a); x1[j] += (b); }

  TF_R(13) TF_R(15) TF_R(26) TF_R(6)
  TF_INJ(ks1, ks2 + 1u)
  TF_R(17) TF_R(29) TF_R(16) TF_R(24)
  TF_INJ(ks2, ks0 + 2u)
  TF_R(13) TF_R(15) TF_R(26) TF_R(6)
  TF_INJ(ks0, ks1 + 3u)
  TF_R(17) TF_R(29) TF_R(16) TF_R(24)
  TF_INJ(ks1, ks2 + 4u)
  TF_R(13) TF_R(15) TF_R(26) TF_R(6)
  TF_INJ(ks2, ks0 + 5u)
#undef TF_R
#undef TF_INJ

#pragma unroll
  for (int j = 0; j < N; ++j) out[j] = x0[j] ^ x1[j];
}

// gumbel = -ln(-ln(u)).
// f = bitcast(bits>>9 | 0x3f800000) - 1 exact (Sterbenz); ref's
// max(tiny, f + tiny) == fmaxf(f, tiny) bit-exactly.
// -ln(-ln u) = -ln2*log2(-log2 u) - ln(ln2): inner negate folds into
// v_log_f32's input modifier, scale+offset is one fma. Error class identical
// to the passing R0/R2 builds (~5e-7 abs in g vs O(1) top-2 gaps).
__device__ __forceinline__ float gumbel_from_bits(uint32_t bits) {
  constexpr float kTiny = 1.17549435e-38f;   // FLT_MIN
  constexpr float kNegLn2 = -0.69314718055994530942f;
  constexpr float kNegLnLn2 = 0.36651292058166432701f;  // -ln(ln 2)
  float f = __uint_as_float((bits >> 9) | 0x3F800000u) - 1.0f;
  float u = fmaxf(f, kTiny);
  float z = __builtin_amdgcn_logf(u);         // log2(u) < 0
  float w = __builtin_amdgcn_logf(-z);        // log2(-log2(u))
  return fmaf(kNegLn2, w, kNegLnLn2);
}

// min-waves 2: VGPR budget up to 256 so the 8 threefry chains + the
// prefetched next-iteration loads can all stay live. TLP of 2-4 waves/SIMD
// plus ILP-8 is ample to cover 4-cyc VALU dep latency and load latency.
__global__ __launch_bounds__(kBlk, 2) void sampler_partial(
    const float* __restrict__ logits, const float* __restrict__ temps,
    Part* __restrict__ parts) {
  const int r = blockIdx.x / kSplit;
  const int g = blockIdx.x % kSplit;
  const float t = temps[r];
  const bool greedy = (t == 0.0f);
  const int start = g * kChunk;
  const int end = start + kChunk;
  const float* __restrict__ row = logits + (size_t)r * kV;

  float best = -__builtin_inff();
  int bi = 0;

  if (greedy) {
    // pure argmax of raw logits, first-occurrence tie-break (strict >)
    for (int v = start + (int)threadIdx.x * kElem; v + (kElem - 1) < end;
         v += kBlk * kElem) {
      float4 a = *reinterpret_cast<const float4*>(row + v);
      float4 b = *reinterpret_cast<const float4*>(row + v + 4);
      float la[8] = {a.x, a.y, a.z, a.w, b.x, b.y, b.z, b.w};
#pragma unroll
      for (int j = 0; j < 8; ++j) {
        if (la[j] > best) { best = la[j]; bi = v + j; }
      }
    }
  } else {
    // argmax(la/t + g) == argmax(la + t*g) for t > 0 (monotonic).
    // Software-pipelined: next iteration's loads are issued BEFORE the
    // current threefry body, so their results are live across ~1300 cycles
    // of compute and the vmcnt wait lands after it, not before.
    int v = start + (int)threadIdx.x * kElem;
    if (v + (kElem - 1) < end) {
      float4 a = *reinterpret_cast<const float4*>(row + v);
      float4 b = *reinterpret_cast<const float4*>(row + v + 4);
      for (;;) {
        const int vn = v + kBlk * kElem;
        const bool has_next = (vn + (kElem - 1) < end);
        const int vp = has_next ? vn : v;   // tail-safe prefetch address
        float4 na = *reinterpret_cast<const float4*>(row + vp);
        float4 nb = *reinterpret_cast<const float4*>(row + vp + 4);

        float la[8] = {a.x, a.y, a.z, a.w, b.x, b.y, b.z, b.w};
        uint32_t bits[8];
        threefry_bits_n<8>((uint32_t)(r * kV + v), bits);  // flat idx < 2^25
#pragma unroll
        for (int j = 0; j < 8; ++j) {
          float key = fmaf(t, gumbel_from_bits(bits[j]), la[j]);
          if (key > best) { best = key; bi = v + j; }
        }

        if (!has_next) break;
        v = vn; a = na; b = nb;
      }
    }
  }

  __shared__ float sv[kBlk];
  __shared__ int si[kBlk];
  sv[threadIdx.x] = best;
  si[threadIdx.x] = bi;
  __syncthreads();
  for (int s = kBlk / 2; s > 0; s >>= 1) {
    if ((int)threadIdx.x < s) {
      float ov = sv[threadIdx.x + s]; int oi = si[threadIdx.x + s];
      float mv = sv[threadIdx.x];     int mi = si[threadIdx.x];
      if (ov > mv || (ov == mv && oi < mi)) {
        sv[threadIdx.x] = ov; si[threadIdx.x] = oi;
      }
    }
    __syncthreads();
  }
  if (threadIdx.x == 0) {
    parts[r * kSplit + g].val = sv[0];
    parts[r * kSplit + g].idx = si[0];
  }
}

__global__ __launch_bounds__(kB) void sampler_final(
    const Part* __restrict__ parts, int* __restrict__ out) {
  const int r = threadIdx.x;
  if (r < kB) {
    float bv = -__builtin_inff();
    int bi = 0;
    for (int g = 0; g < kSplit; ++g) {
      Part p = parts[r * kSplit + g];
      if (p.val > bv || (p.val == bv && p.idx < bi)) { bv = p.val; bi = p.idx; }
    }
    out[r] = bi;
  }
}

}  // namespace

extern "C" void kernel_launch(void* const* d_in, const int* in_sizes, int n_in,
                              void* d_out, int out_size, void* d_ws, size_t ws_size,
                              hipStream_t stream) {
  const float* logits = (const float*)d_in[0];
  const float* temps = (const float*)d_in[1];
  int* out = (int*)d_out;
  Part* parts = (Part*)d_ws;  // kB * kSplit * 8 B = 16 KiB

  sampler_partial<<<dim3(kB * kSplit), dim3(kBlk), 0, stream>>>(logits, temps, parts);
  sampler_final<<<dim3(1), dim3(kB), 0, stream>>>(parts, out);
}